// Round 3
// baseline (485.531 us; speedup 1.0000x reference)
//
#include <hip/hip_runtime.h>
#include <stdint.h>

typedef unsigned short u16;
typedef unsigned int   u32;
typedef __attribute__((ext_vector_type(4))) float f32x4;
typedef __attribute__((ext_vector_type(8))) short s16x8;
typedef __attribute__((ext_vector_type(8))) u16   u16x8;
typedef __attribute__((ext_vector_type(4))) u32   u32x4;
typedef __attribute__((ext_vector_type(2))) u32   u32x2;

#define K_DIM 4096
#define N_DIM 11008
#define M_DIMQ 4096

static __device__ __forceinline__ u16 f2bf(float f) {
  __bf16 b = (__bf16)f;
  return __builtin_bit_cast(u16, b);
}

// Single source of truth for the swizzled LDS address (u16 units).
// Writers pass (row, source_chunk); readers pass (row, desired_chunk).
// slot = chunk ^ (row&7) is an involution => read(desired) hits write(source==desired).
static __device__ __forceinline__ int lds_off(int row, int chunk) {
  return row * 64 + (chunk ^ (row & 7)) * 8;
}

__global__ __launch_bounds__(256, 3) void wq_gemm(
    const float* __restrict__ X,   // [4096, 4096] f32 (f16 promoted by harness)
    const u32* __restrict__ QW,    // [11008, 512] int32 (8 nibbles each)
    const u32* __restrict__ QZ,    // [11008, 4]  int32
    const float* __restrict__ SC,  // [11008, 32] f32
    const float* __restrict__ BI,  // [11008] f32
    float*       __restrict__ OUT) // [4096, 11008] f32
{
  __shared__ __align__(16) u16 As[128 * 64];   // [row][slot] 16B chunks, XOR-swizzled, bf16
  __shared__ __align__(16) u16 Bs[128 * 64];
  __shared__ u32 ZS[128 * 33];                 // per n-row: bf16(scale) bits | z<<16

  const int tid  = threadIdx.x;
  const int lane = tid & 63;
  const int wid  = tid >> 6;
  const int n0   = blockIdx.x * 128;
  const int m0   = blockIdx.y * 128;

  // ---------------- prologue: zeros/scales table ----------------
  {
    const int nl = tid >> 1;          // 0..127
    const int h  = tid & 1;           // group half
    const int n  = n0 + nl;
    u32x2 qz = *(const u32x2*)(QZ + n * 4 + h * 2);
    const float* sp = SC + n * 32 + h * 16;
#pragma unroll
    for (int j = 0; j < 16; ++j) {
      u32 zi = (((j < 8) ? qz.x : qz.y) >> ((j & 7) * 4)) & 15u;
      ZS[nl * 33 + h * 16 + j] = (u32)f2bf(sp[j]) | (zi << 16);
    }
  }

  f32x4 acc[4][4];
#pragma unroll
  for (int i = 0; i < 4; ++i)
#pragma unroll
    for (int j = 0; j < 4; ++j) acc[i][j] = (f32x4)0.0f;

  const int wr  = wid >> 1;       // wave row 0..1
  const int wc  = wid & 1;        // wave col 0..1
  const int qq  = lane >> 4;      // 0..3
  const int r16 = lane & 15;

  // A staging: thread -> (rows tid>>3 + 32*i, chunk tid&7 = 8 consecutive k)
  const int a_row = tid >> 3;     // 0..31
  const int a_ch  = tid & 7;
  const float* a_src = X + (size_t)(m0 + a_row) * K_DIM + a_ch * 8;

  // B dequant: thread -> (row tid>>1, chunks (tid&1)*4 .. +3)
  const int nl_dq = tid >> 1;
  const int h_dq  = tid & 1;
  const u32* qw_row = QW + (size_t)(n0 + nl_dq) * (K_DIM / 8) + h_dq * 4;

  for (int kt = 0; kt < 64; ++kt) {
    // issue global loads early — latency hides under previous MFMA phase + barrier
    f32x4 a_lo[4], a_hi[4];
#pragma unroll
    for (int i = 0; i < 4; ++i) {
      const float* p = a_src + (size_t)(32 * i) * K_DIM + kt * 64;
      a_lo[i] = *(const f32x4*)p;
      a_hi[i] = *(const f32x4*)(p + 4);
    }
    u32x4 qv = *(const u32x4*)(qw_row + kt * 8);

    __syncthreads();   // (1) previous tile fully consumed (covers ZS on kt==0)

    // A regs (f32) -> bf16 -> swizzled LDS
#pragma unroll
    for (int i = 0; i < 4; ++i) {
      u16x8 w;
#pragma unroll
      for (int j = 0; j < 4; ++j) {
        w[j]     = f2bf(a_lo[i][j]);
        w[j + 4] = f2bf(a_hi[i][j]);
      }
      *(u16x8*)(As + lds_off(a_row + 32 * i, a_ch)) = w;
    }

    // group constants (f32 'c': c = -(128+z)*s, exact from bf16 s)
    const int g = kt >> 1;
    const u32 zs = ZS[nl_dq * 33 + g];
    const float sc = __uint_as_float((zs & 0xFFFFu) << 16);
    const float cc = -(float)((zs >> 16) + 128u) * sc;

    // dequant 4 int32 -> 32 bf16 -> swizzled LDS
#pragma unroll
    for (int i = 0; i < 4; ++i) {
      const u32 q = qv[i];
      u16x8 w;
#pragma unroll
      for (int j = 0; j < 8; ++j) {
        u32 fb = 0x43000000u | (((q >> (4 * j)) & 15u) << 16);  // f32 = 128 + nib (exact)
        w[j] = f2bf(__uint_as_float(fb) * sc + cc);
      }
      *(u16x8*)(Bs + lds_off(nl_dq, h_dq * 4 + i)) = w;
    }

    __syncthreads();   // (2) tile staged

    // MFMA: 2 k-sub-steps of 32, 4x4 fragments per wave
#pragma unroll
    for (int s = 0; s < 2; ++s) {
      s16x8 af[4], bfr[4];
#pragma unroll
      for (int mi = 0; mi < 4; ++mi)
        af[mi] = *(const s16x8*)(As + lds_off(wr * 64 + mi * 16 + r16, s * 4 + qq));
#pragma unroll
      for (int ni = 0; ni < 4; ++ni)
        bfr[ni] = *(const s16x8*)(Bs + lds_off(wc * 64 + ni * 16 + r16, s * 4 + qq));
#pragma unroll
      for (int mi = 0; mi < 4; ++mi)
#pragma unroll
        for (int ni = 0; ni < 4; ++ni)
          acc[mi][ni] = __builtin_amdgcn_mfma_f32_16x16x32_bf16(
              af[mi], bfr[ni], acc[mi][ni], 0, 0, 0);
    }
  }

  // ---------------- epilogue: bias + store (f32) ----------------
  float bias[4];
#pragma unroll
  for (int ni = 0; ni < 4; ++ni)
    bias[ni] = BI[n0 + wc * 64 + ni * 16 + r16];

#pragma unroll
  for (int mi = 0; mi < 4; ++mi) {
#pragma unroll
    for (int rr = 0; rr < 4; ++rr) {
      const int row = m0 + wr * 64 + mi * 16 + qq * 4 + rr;
      float* op = OUT + (size_t)row * N_DIM + n0 + wc * 64;
#pragma unroll
      for (int ni = 0; ni < 4; ++ni)
        op[ni * 16 + r16] = acc[mi][ni][rr] + bias[ni];
    }
  }
}

extern "C" void kernel_launch(void* const* d_in, const int* in_sizes, int n_in,
                              void* d_out, int out_size, void* d_ws, size_t ws_size,
                              hipStream_t stream) {
  const float* X  = (const float*)d_in[0];
  const u32*   QW = (const u32*)d_in[1];
  const u32*   QZ = (const u32*)d_in[2];
  const float* SC = (const float*)d_in[3];
  const float* BI = (const float*)d_in[4];
  float* OUT = (float*)d_out;

  dim3 grid(N_DIM / 128, M_DIMQ / 128);  // 86 x 32
  wq_gemm<<<grid, 256, 0, stream>>>(X, QW, QZ, SC, BI, OUT);
}

// Round 4
// 381.530 us; speedup vs baseline: 1.2726x; 1.2726x over previous
//
#include <hip/hip_runtime.h>
#include <stdint.h>

typedef unsigned short u16;
typedef unsigned int   u32;
typedef __attribute__((ext_vector_type(4))) float f32x4;
typedef __attribute__((ext_vector_type(8))) short s16x8;
typedef __attribute__((ext_vector_type(8))) u16   u16x8;
typedef __attribute__((ext_vector_type(4))) u32   u32x4;
typedef __attribute__((ext_vector_type(2))) u32   u32x2;

#define K_DIM 4096
#define N_DIM 11008
#define M_DIMQ 4096

static __device__ __forceinline__ u16 f2bf(float f) {
  __bf16 b = (__bf16)f;
  return __builtin_bit_cast(u16, b);
}

// =================== pre-pass 1: X f32 -> bf16 ===================
__global__ __launch_bounds__(256) void cvt_x(const float* __restrict__ X,
                                             u16* __restrict__ Xb) {
  const size_t i = ((size_t)blockIdx.x * 256 + threadIdx.x) * 8;
  f32x4 a = *(const f32x4*)(X + i);
  f32x4 b = *(const f32x4*)(X + i + 4);
  u16x8 w;
#pragma unroll
  for (int j = 0; j < 4; ++j) { w[j] = f2bf(a[j]); w[j + 4] = f2bf(b[j]); }
  *(u16x8*)(Xb + i) = w;
}

// =================== pre-pass 2: int4 W -> bf16 ===================
__global__ __launch_bounds__(256) void dq_w(const u32* __restrict__ QW,
                                            const u32* __restrict__ QZ,
                                            const float* __restrict__ SC,
                                            u16* __restrict__ Wb) {
  const int idx = blockIdx.x * 256 + threadIdx.x;   // < 11008*128
  const int row = idx >> 7;
  const int kq  = idx & 127;        // which u32x4 along K
  const int g   = kq >> 2;          // quant group 0..31
  const u32 sb  = f2bf(SC[row * 32 + g]);
  const float sc = __uint_as_float(sb << 16);
  const u32 z   = (QZ[row * 4 + (g >> 3)] >> ((g & 7) * 4)) & 15u;
  const float cc = -(float)(z + 128u) * sc;
  u32x4 q = *(const u32x4*)(QW + (size_t)row * 512 + kq * 4);
  u16* op = Wb + (size_t)row * K_DIM + kq * 32;
#pragma unroll
  for (int ji = 0; ji < 4; ++ji) {
    const u32 qv = q[ji];
    u16x8 w;
#pragma unroll
    for (int j = 0; j < 8; ++j) {
      u32 fb = 0x43000000u | (((qv >> (4 * j)) & 15u) << 16);  // f32 = 128 + nib (exact)
      w[j] = f2bf(__uint_as_float(fb) * sc + cc);
    }
    *(u16x8*)(op + ji * 8) = w;
  }
}

// =================== main GEMM: 256x256 tile, BK=64, 8 waves ===================
__global__ __launch_bounds__(512, 2) void wq_gemm2(
    const u16* __restrict__ Xb,   // [4096,4096] bf16
    const u16* __restrict__ Wb,   // [11008,4096] bf16
    const float* __restrict__ BI,
    float* __restrict__ OUT)
{
  // [dbuf][op A=0/B=1][half(128 rows)][128 rows * 64 cols bf16], XOR-swizzled 16B chunks
  __shared__ __align__(16) u16 lds[2][2][2][8192];   // 128 KiB

  const int tid  = threadIdx.x;
  const int lane = tid & 63;
  const int wid  = tid >> 6;
  const int n0   = blockIdx.x * 256;
  const int m0   = blockIdx.y * 256;

  const int wr  = wid >> 2;      // 0..1 : M half (128 rows)
  const int wc  = wid & 3;       // 0..3 : N quarter (64 cols)
  const int qq  = lane >> 4;     // 0..3
  const int r16 = lane & 15;

  // staging geometry: issue (h,i): lds o16 = i*512 + tid -> row = i*64 + (tid>>3), slot = tid&7
  // source must carry chunk c = slot ^ (row&7)  (involution with read side)
  const int srow = tid >> 3;                    // 0..63
  const int sch  = (tid & 7) ^ (srow & 7);

  // stage one K-tile t into buffer buf (8 x global_load_lds, 16B each)
  auto stage = [&](int t, int buf) {
#pragma unroll
    for (int h = 0; h < 2; ++h) {
#pragma unroll
      for (int i = 0; i < 2; ++i) {
        const u16* srcA = Xb + (size_t)(m0 + h * 128 + i * 64 + srow) * K_DIM + t * 64 + sch * 8;
        u16* dstA = (u16*)&lds[buf][0][h][(i * 512 + wid * 64) * 8];
        __builtin_amdgcn_global_load_lds(
            (const __attribute__((address_space(1))) void*)srcA,
            (__attribute__((address_space(3))) void*)dstA, 16, 0, 0);
        const u16* srcB = Wb + (size_t)(n0 + h * 128 + i * 64 + srow) * K_DIM + t * 64 + sch * 8;
        u16* dstB = (u16*)&lds[buf][1][h][(i * 512 + wid * 64) * 8];
        __builtin_amdgcn_global_load_lds(
            (const __attribute__((address_space(1))) void*)srcB,
            (__attribute__((address_space(3))) void*)dstB, 16, 0, 0);
      }
    }
  };

  f32x4 acc[8][4];
#pragma unroll
  for (int i = 0; i < 8; ++i)
#pragma unroll
    for (int j = 0; j < 4; ++j) acc[i][j] = (f32x4)0.0f;

  stage(0, 0);
  __syncthreads();   // drains vmcnt -> tile 0 resident

  for (int t = 0; t < 64; ++t) {
    if (t < 63) stage(t + 1, (t + 1) & 1);   // issue-early: full compute window to land

    const u16* LA = &lds[t & 1][0][wr][0];          // this wave's A half (128 rows)
    const u16* LB = &lds[t & 1][1][wc >> 1][0];     // this wave's B half (128 rows)
    const int brow0 = (wc & 1) * 64;

#pragma unroll
    for (int s = 0; s < 2; ++s) {
      s16x8 af[8], bfr[4];
#pragma unroll
      for (int mi = 0; mi < 8; ++mi) {
        const int row = mi * 16 + r16;
        const int sl = (s * 4 + qq) ^ (row & 7);
        af[mi] = *(const s16x8*)(LA + row * 64 + sl * 8);
      }
#pragma unroll
      for (int ni = 0; ni < 4; ++ni) {
        const int row = brow0 + ni * 16 + r16;
        const int sl = (s * 4 + qq) ^ (row & 7);
        bfr[ni] = *(const s16x8*)(LB + row * 64 + sl * 8);
      }
      __builtin_amdgcn_s_setprio(1);
#pragma unroll
      for (int mi = 0; mi < 8; ++mi)
#pragma unroll
        for (int ni = 0; ni < 4; ++ni)
          acc[mi][ni] = __builtin_amdgcn_mfma_f32_16x16x32_bf16(
              af[mi], bfr[ni], acc[mi][ni], 0, 0, 0);
      __builtin_amdgcn_s_setprio(0);
    }
    __syncthreads();   // all waves done reading buf[t&1]; own t+1 loads drained
  }

  // epilogue: bias + f32 store
  float bias[4];
#pragma unroll
  for (int ni = 0; ni < 4; ++ni)
    bias[ni] = BI[n0 + wc * 64 + ni * 16 + r16];
#pragma unroll
  for (int mi = 0; mi < 8; ++mi) {
#pragma unroll
    for (int rr = 0; rr < 4; ++rr) {
      const int row = m0 + wr * 128 + mi * 16 + qq * 4 + rr;
      float* op = OUT + (size_t)row * N_DIM + n0 + wc * 64;
#pragma unroll
      for (int ni = 0; ni < 4; ++ni)
        op[ni * 16 + r16] = acc[mi][ni][rr] + bias[ni];
    }
  }
}

// =================== fallback: round-3 fused kernel (proven PASS) ===================
static __device__ __forceinline__ int lds_off(int row, int chunk) {
  return row * 64 + (chunk ^ (row & 7)) * 8;
}

__global__ __launch_bounds__(256, 3) void wq_gemm(
    const float* __restrict__ X, const u32* __restrict__ QW,
    const u32* __restrict__ QZ, const float* __restrict__ SC,
    const float* __restrict__ BI, float* __restrict__ OUT)
{
  __shared__ __align__(16) u16 As[128 * 64];
  __shared__ __align__(16) u16 Bs[128 * 64];
  __shared__ u32 ZS[128 * 33];

  const int tid  = threadIdx.x;
  const int lane = tid & 63;
  const int wid  = tid >> 6;
  const int n0   = blockIdx.x * 128;
  const int m0   = blockIdx.y * 128;

  {
    const int nl = tid >> 1;
    const int h  = tid & 1;
    const int n  = n0 + nl;
    u32x2 qz = *(const u32x2*)(QZ + n * 4 + h * 2);
    const float* sp = SC + n * 32 + h * 16;
#pragma unroll
    for (int j = 0; j < 16; ++j) {
      u32 zi = (((j < 8) ? qz.x : qz.y) >> ((j & 7) * 4)) & 15u;
      ZS[nl * 33 + h * 16 + j] = (u32)f2bf(sp[j]) | (zi << 16);
    }
  }

  f32x4 acc[4][4];
#pragma unroll
  for (int i = 0; i < 4; ++i)
#pragma unroll
    for (int j = 0; j < 4; ++j) acc[i][j] = (f32x4)0.0f;

  const int wr = wid >> 1, wc = wid & 1, qq = lane >> 4, r16 = lane & 15;
  const int a_row = tid >> 3, a_ch = tid & 7;
  const float* a_src = X + (size_t)(m0 + a_row) * K_DIM + a_ch * 8;
  const int nl_dq = tid >> 1, h_dq = tid & 1;
  const u32* qw_row = QW + (size_t)(n0 + nl_dq) * (K_DIM / 8) + h_dq * 4;

  for (int kt = 0; kt < 64; ++kt) {
    f32x4 a_lo[4], a_hi[4];
#pragma unroll
    for (int i = 0; i < 4; ++i) {
      const float* p = a_src + (size_t)(32 * i) * K_DIM + kt * 64;
      a_lo[i] = *(const f32x4*)p;
      a_hi[i] = *(const f32x4*)(p + 4);
    }
    u32x4 qv = *(const u32x4*)(qw_row + kt * 8);
    __syncthreads();
#pragma unroll
    for (int i = 0; i < 4; ++i) {
      u16x8 w;
#pragma unroll
      for (int j = 0; j < 4; ++j) { w[j] = f2bf(a_lo[i][j]); w[j + 4] = f2bf(a_hi[i][j]); }
      *(u16x8*)(As + lds_off(a_row + 32 * i, a_ch)) = w;
    }
    const int g = kt >> 1;
    const u32 zs = ZS[nl_dq * 33 + g];
    const float sc = __uint_as_float((zs & 0xFFFFu) << 16);
    const float cc = -(float)((zs >> 16) + 128u) * sc;
#pragma unroll
    for (int i = 0; i < 4; ++i) {
      const u32 q = qv[i];
      u16x8 w;
#pragma unroll
      for (int j = 0; j < 8; ++j) {
        u32 fb = 0x43000000u | (((q >> (4 * j)) & 15u) << 16);
        w[j] = f2bf(__uint_as_float(fb) * sc + cc);
      }
      *(u16x8*)(Bs + lds_off(nl_dq, h_dq * 4 + i)) = w;
    }
    __syncthreads();
#pragma unroll
    for (int s = 0; s < 2; ++s) {
      s16x8 af[4], bfr[4];
#pragma unroll
      for (int mi = 0; mi < 4; ++mi)
        af[mi] = *(const s16x8*)(As + lds_off(wr * 64 + mi * 16 + r16, s * 4 + qq));
#pragma unroll
      for (int ni = 0; ni < 4; ++ni)
        bfr[ni] = *(const s16x8*)(Bs + lds_off(wc * 64 + ni * 16 + r16, s * 4 + qq));
#pragma unroll
      for (int mi = 0; mi < 4; ++mi)
#pragma unroll
        for (int ni = 0; ni < 4; ++ni)
          acc[mi][ni] = __builtin_amdgcn_mfma_f32_16x16x32_bf16(
              af[mi], bfr[ni], acc[mi][ni], 0, 0, 0);
    }
  }

  float bias[4];
#pragma unroll
  for (int ni = 0; ni < 4; ++ni) bias[ni] = BI[n0 + wc * 64 + ni * 16 + r16];
#pragma unroll
  for (int mi = 0; mi < 4; ++mi)
#pragma unroll
    for (int rr = 0; rr < 4; ++rr) {
      const int row = m0 + wr * 64 + mi * 16 + qq * 4 + rr;
      float* op = OUT + (size_t)row * N_DIM + n0 + wc * 64;
#pragma unroll
      for (int ni = 0; ni < 4; ++ni)
        op[ni * 16 + r16] = acc[mi][ni][rr] + bias[ni];
    }
}

extern "C" void kernel_launch(void* const* d_in, const int* in_sizes, int n_in,
                              void* d_out, int out_size, void* d_ws, size_t ws_size,
                              hipStream_t stream) {
  const float* X  = (const float*)d_in[0];
  const u32*   QW = (const u32*)d_in[1];
  const u32*   QZ = (const u32*)d_in[2];
  const float* SC = (const float*)d_in[3];
  const float* BI = (const float*)d_in[4];
  float* OUT = (float*)d_out;

  const size_t XB_BYTES = (size_t)M_DIMQ * K_DIM * 2;         // 33.5 MB
  const size_t WB_BYTES = (size_t)N_DIM * K_DIM * 2;          // 90.2 MB
  if (ws_size >= XB_BYTES + WB_BYTES) {
    u16* Xb = (u16*)d_ws;
    u16* Wb = (u16*)((char*)d_ws + XB_BYTES);
    cvt_x<<<(M_DIMQ * K_DIM / 8) / 256, 256, 0, stream>>>(X, Xb);
    dq_w<<<(N_DIM * 128) / 256, 256, 0, stream>>>(QW, QZ, SC, Wb);
    dim3 grid2(N_DIM / 256, M_DIMQ / 256);   // 43 x 16
    wq_gemm2<<<grid2, 512, 0, stream>>>(Xb, Wb, BI, OUT);
  } else {
    dim3 grid(N_DIM / 128, M_DIMQ / 128);    // 86 x 32
    wq_gemm<<<grid, 256, 0, stream>>>(X, QW, QZ, SC, BI, OUT);
  }
}

// Round 5
// 359.633 us; speedup vs baseline: 1.3501x; 1.0609x over previous
//
#include <hip/hip_runtime.h>
#include <stdint.h>

typedef unsigned short u16;
typedef unsigned int   u32;
typedef __attribute__((ext_vector_type(4))) float f32x4;
typedef __attribute__((ext_vector_type(8))) short s16x8;
typedef __attribute__((ext_vector_type(8))) u16   u16x8;
typedef __attribute__((ext_vector_type(4))) u32   u32x4;
typedef __attribute__((ext_vector_type(2))) u32   u32x2;

#define K_DIM 4096
#define N_DIM 11008
#define M_DIMQ 4096

static __device__ __forceinline__ u16 f2bf(float f) {
  __bf16 b = (__bf16)f;
  return __builtin_bit_cast(u16, b);
}

// piece-linear position o (0..1023) <-> (row 0..255, chunk 0..3)
// line = o>>3, slot = o&7; s' = slot ^ (line&7); row = 2*line + (s'>>2); chunk = s'&3
// Readers at (row,chunk) use slot = (chunk + 4*(row&1)) ^ (line&7)  [involution]
static __device__ __forceinline__ void o_decode(int o, int& row, int& ch) {
  const int l = o >> 3;
  const int sp = (o & 7) ^ (l & 7);
  row = 2 * l + (sp >> 2);
  ch = sp & 3;
}

// ============ pre-pass 1: X f32 -> bf16, piece-linear layout ============
// Xb layout: [M/256][K/32][1024 positions][8 bf16]
__global__ __launch_bounds__(256) void cvt_x_perm(const float* __restrict__ X,
                                                  u16* __restrict__ Xb) {
  const int gid = blockIdx.x * 256 + threadIdx.x;
  const int o = gid & 1023, h = (gid >> 10) & 127, R = gid >> 17;
  int row, ch; o_decode(o, row, ch);
  const float* src = X + (size_t)(R * 256 + row) * K_DIM + h * 32 + ch * 8;
  f32x4 a = *(const f32x4*)src;
  f32x4 b = *(const f32x4*)(src + 4);
  u16x8 w;
#pragma unroll
  for (int j = 0; j < 4; ++j) { w[j] = f2bf(a[j]); w[j + 4] = f2bf(b[j]); }
  *(u16x8*)(Xb + (size_t)gid * 8) = w;
}

// ============ pre-pass 2: int4 W -> bf16, piece-linear layout ============
// Wb layout: [N/256][K/32][1024][8]
__global__ __launch_bounds__(256) void dq_w_perm(const u32* __restrict__ QW,
                                                 const u32* __restrict__ QZ,
                                                 const float* __restrict__ SC,
                                                 u16* __restrict__ Wb) {
  const int gid = blockIdx.x * 256 + threadIdx.x;
  const int o = gid & 1023, h = (gid >> 10) & 127, R = gid >> 17;
  int row, ch; o_decode(o, row, ch);
  const int nrow = R * 256 + row;
  const int g = h >> 2;                       // quant group
  const float sc = __uint_as_float(((u32)f2bf(SC[nrow * 32 + g])) << 16);
  const u32 z = (QZ[nrow * 4 + (g >> 3)] >> ((g & 7) * 4)) & 15u;
  const float cc = -(float)(z + 128u) * sc;
  const u32 q = QW[(size_t)nrow * 512 + h * 4 + ch];
  u16x8 w;
#pragma unroll
  for (int j = 0; j < 8; ++j) {
    u32 fb = 0x43000000u | (((q >> (4 * j)) & 15u) << 16);  // f32 = 128 + nib (exact)
    w[j] = f2bf(__uint_as_float(fb) * sc + cc);
  }
  *(u16x8*)(Wb + (size_t)gid * 8) = w;
}

// ============ main GEMM: 256x256 tile, K-step 32, 4-slot ring, counted vmcnt ============
#define SLOT_U16 16384   // A piece (8192) + B piece (8192)

__global__ __launch_bounds__(512, 2) void wq_gemm3(
    const u16* __restrict__ Xb,   // [16][128][1024][8]
    const u16* __restrict__ Wb,   // [43][128][1024][8]
    const float* __restrict__ BI,
    float* __restrict__ OUT)
{
  __shared__ __align__(16) u16 lds[4 * SLOT_U16];   // 128 KiB

  const int tid  = threadIdx.x;
  const int lane = tid & 63;
  const int wid  = tid >> 6;

  // bijective XCD swizzle (688 blocks, 688%8==0 -> simple form)
  const int lin = blockIdx.y * 43 + blockIdx.x;
  const int swz = (lin & 7) * 86 + (lin >> 3);
  const int bn  = swz % 43;
  const int bm  = swz / 43;
  const int n0  = bn * 256;
  const int m0  = bm * 256;

  const int wr  = wid >> 2;      // 0..1 : M half (128 rows)
  const int wc  = wid & 3;       // 0..3 : N quarter (64 cols)
  const int qq  = lane >> 4;     // 0..3 : k-chunk
  const int r16 = lane & 15;
  const int r2  = r16 >> 1;

  // per-lane LDS read constants (u16 units)
  const int slot_a = (qq + 4 * (r16 & 1)) ^ r2;          // r2 in 0..7
  const int a_off  = wr * 4096 + r2 * 64 + slot_a * 8;   // + mi*512
  const int b_off  = wc * 2048 + r2 * 64 + slot_a * 8;   // + ni*512 (B piece base added later)

  // staging pointers: piece for K-half h lives at base + h*8192 (u16)
  const u16* aS0 = Xb + (size_t)bm * 128 * 8192 + (size_t)(0 * 512 + tid) * 8;
  const u16* aS1 = Xb + (size_t)bm * 128 * 8192 + (size_t)(1 * 512 + tid) * 8;
  const u16* bS0 = Wb + (size_t)bn * 128 * 8192 + (size_t)(0 * 512 + tid) * 8;
  const u16* bS1 = Wb + (size_t)bn * 128 * 8192 + (size_t)(1 * 512 + tid) * 8;
  const int dA0 = wid * 512;            // wave-uniform LDS dest offsets (u16)
  const int dA1 = 4096 + wid * 512;
  const int dB0 = 8192 + wid * 512;
  const int dB1 = 8192 + 4096 + wid * 512;

#define STAGE(H) {                                                              \
    const int sb = ((H) & 3) * SLOT_U16;                                        \
    const size_t ko = (size_t)(H) * 8192;                                       \
    __builtin_amdgcn_global_load_lds(                                           \
        (const __attribute__((address_space(1))) void*)(aS0 + ko),              \
        (__attribute__((address_space(3))) void*)(lds + sb + dA0), 16, 0, 0);   \
    __builtin_amdgcn_global_load_lds(                                           \
        (const __attribute__((address_space(1))) void*)(aS1 + ko),              \
        (__attribute__((address_space(3))) void*)(lds + sb + dA1), 16, 0, 0);   \
    __builtin_amdgcn_global_load_lds(                                           \
        (const __attribute__((address_space(1))) void*)(bS0 + ko),              \
        (__attribute__((address_space(3))) void*)(lds + sb + dB0), 16, 0, 0);   \
    __builtin_amdgcn_global_load_lds(                                           \
        (const __attribute__((address_space(1))) void*)(bS1 + ko),              \
        (__attribute__((address_space(3))) void*)(lds + sb + dB1), 16, 0, 0);   \
  }

  f32x4 acc[8][4];
#pragma unroll
  for (int i = 0; i < 8; ++i)
#pragma unroll
    for (int j = 0; j < 4; ++j) acc[i][j] = (f32x4)0.0f;

  // prologue: stage pairs 0,1,2 into slots 0,1,2 (12 loads outstanding)
  STAGE(0); STAGE(1); STAGE(2);

#define KSTEP(H, VMSTR, DOSTAGE) {                                              \
    asm volatile("s_waitcnt vmcnt(" VMSTR ")" ::: "memory");                    \
    __builtin_amdgcn_s_barrier();                                               \
    __builtin_amdgcn_sched_barrier(0);                                          \
    if (DOSTAGE) STAGE((H) + 3);                                                \
    const u16* base = lds + ((H) & 3) * SLOT_U16;                               \
    const u16* pA = base + a_off;                                               \
    const u16* pB = base + 8192 + b_off;                                        \
    s16x8 af[8], bfr[4];                                                        \
    _Pragma("unroll")                                                           \
    for (int mi = 0; mi < 8; ++mi) af[mi] = *(const s16x8*)(pA + mi * 512);     \
    _Pragma("unroll")                                                           \
    for (int ni = 0; ni < 4; ++ni) bfr[ni] = *(const s16x8*)(pB + ni * 512);    \
    __builtin_amdgcn_s_setprio(1);                                              \
    _Pragma("unroll")                                                           \
    for (int mi = 0; mi < 8; ++mi)                                              \
      _Pragma("unroll")                                                         \
      for (int ni = 0; ni < 4; ++ni)                                            \
        acc[mi][ni] = __builtin_amdgcn_mfma_f32_16x16x32_bf16(                  \
            af[mi], bfr[ni], acc[mi][ni], 0, 0, 0);                             \
    __builtin_amdgcn_s_setprio(0);                                              \
  }

  // main: h = 0..124 stage h+3; h=125 no stage; tails shrink vmcnt
#pragma unroll 4
  for (int h = 0; h < 125; ++h) KSTEP(h, "8", true);
  KSTEP(125, "8", false);
  KSTEP(126, "4", false);
  KSTEP(127, "0", false);

  // epilogue: bias + f32 store
  float bias[4];
#pragma unroll
  for (int ni = 0; ni < 4; ++ni)
    bias[ni] = BI[n0 + wc * 64 + ni * 16 + r16];
#pragma unroll
  for (int mi = 0; mi < 8; ++mi) {
#pragma unroll
    for (int rr = 0; rr < 4; ++rr) {
      const int row = m0 + wr * 128 + mi * 16 + qq * 4 + rr;
      float* op = OUT + (size_t)row * N_DIM + n0 + wc * 64;
#pragma unroll
      for (int ni = 0; ni < 4; ++ni)
        op[ni * 16 + r16] = acc[mi][ni][rr] + bias[ni];
    }
  }
}

// ============ fallback: round-3 fused kernel (proven PASS) ============
static __device__ __forceinline__ int lds_off(int row, int chunk) {
  return row * 64 + (chunk ^ (row & 7)) * 8;
}

__global__ __launch_bounds__(256, 3) void wq_gemm(
    const float* __restrict__ X, const u32* __restrict__ QW,
    const u32* __restrict__ QZ, const float* __restrict__ SC,
    const float* __restrict__ BI, float* __restrict__ OUT)
{
  __shared__ __align__(16) u16 As[128 * 64];
  __shared__ __align__(16) u16 Bs[128 * 64];
  __shared__ u32 ZS[128 * 33];

  const int tid  = threadIdx.x;
  const int lane = tid & 63;
  const int wid  = tid >> 6;
  const int n0   = blockIdx.x * 128;
  const int m0   = blockIdx.y * 128;

  {
    const int nl = tid >> 1, h = tid & 1, n = n0 + nl;
    u32x2 qz = *(const u32x2*)(QZ + n * 4 + h * 2);
    const float* sp = SC + n * 32 + h * 16;
#pragma unroll
    for (int j = 0; j < 16; ++j) {
      u32 zi = (((j < 8) ? qz.x : qz.y) >> ((j & 7) * 4)) & 15u;
      ZS[nl * 33 + h * 16 + j] = (u32)f2bf(sp[j]) | (zi << 16);
    }
  }

  f32x4 acc[4][4];
#pragma unroll
  for (int i = 0; i < 4; ++i)
#pragma unroll
    for (int j = 0; j < 4; ++j) acc[i][j] = (f32x4)0.0f;

  const int wr = wid >> 1, wc = wid & 1, qq = lane >> 4, r16 = lane & 15;
  const int a_row = tid >> 3, a_ch = tid & 7;
  const float* a_src = X + (size_t)(m0 + a_row) * K_DIM + a_ch * 8;
  const int nl_dq = tid >> 1, h_dq = tid & 1;
  const u32* qw_row = QW + (size_t)(n0 + nl_dq) * (K_DIM / 8) + h_dq * 4;

  for (int kt = 0; kt < 64; ++kt) {
    f32x4 a_lo[4], a_hi[4];
#pragma unroll
    for (int i = 0; i < 4; ++i) {
      const float* p = a_src + (size_t)(32 * i) * K_DIM + kt * 64;
      a_lo[i] = *(const f32x4*)p;
      a_hi[i] = *(const f32x4*)(p + 4);
    }
    u32x4 qv = *(const u32x4*)(qw_row + kt * 8);
    __syncthreads();
#pragma unroll
    for (int i = 0; i < 4; ++i) {
      u16x8 w;
#pragma unroll
      for (int j = 0; j < 4; ++j) { w[j] = f2bf(a_lo[i][j]); w[j + 4] = f2bf(a_hi[i][j]); }
      *(u16x8*)(As + lds_off(a_row + 32 * i, a_ch)) = w;
    }
    const int g = kt >> 1;
    const u32 zs = ZS[nl_dq * 33 + g];
    const float sc = __uint_as_float((zs & 0xFFFFu) << 16);
    const float cc = -(float)((zs >> 16) + 128u) * sc;
#pragma unroll
    for (int i = 0; i < 4; ++i) {
      const u32 q = qv[i];
      u16x8 w;
#pragma unroll
      for (int j = 0; j < 8; ++j) {
        u32 fb = 0x43000000u | (((q >> (4 * j)) & 15u) << 16);
        w[j] = f2bf(__uint_as_float(fb) * sc + cc);
      }
      *(u16x8*)(Bs + lds_off(nl_dq, h_dq * 4 + i)) = w;
    }
    __syncthreads();
#pragma unroll
    for (int s = 0; s < 2; ++s) {
      s16x8 af[4], bfr[4];
#pragma unroll
      for (int mi = 0; mi < 4; ++mi)
        af[mi] = *(const s16x8*)(As + lds_off(wr * 64 + mi * 16 + r16, s * 4 + qq));
#pragma unroll
      for (int ni = 0; ni < 4; ++ni)
        bfr[ni] = *(const s16x8*)(Bs + lds_off(wc * 64 + ni * 16 + r16, s * 4 + qq));
#pragma unroll
      for (int mi = 0; mi < 4; ++mi)
#pragma unroll
        for (int ni = 0; ni < 4; ++ni)
          acc[mi][ni] = __builtin_amdgcn_mfma_f32_16x16x32_bf16(
              af[mi], bfr[ni], acc[mi][ni], 0, 0, 0);
    }
  }

  float bias[4];
#pragma unroll
  for (int ni = 0; ni < 4; ++ni) bias[ni] = BI[n0 + wc * 64 + ni * 16 + r16];
#pragma unroll
  for (int mi = 0; mi < 4; ++mi)
#pragma unroll
    for (int rr = 0; rr < 4; ++rr) {
      const int row = m0 + wr * 64 + mi * 16 + qq * 4 + rr;
      float* op = OUT + (size_t)row * N_DIM + n0 + wc * 64;
#pragma unroll
      for (int ni = 0; ni < 4; ++ni)
        op[ni * 16 + r16] = acc[mi][ni][rr] + bias[ni];
    }
}

extern "C" void kernel_launch(void* const* d_in, const int* in_sizes, int n_in,
                              void* d_out, int out_size, void* d_ws, size_t ws_size,
                              hipStream_t stream) {
  const float* X  = (const float*)d_in[0];
  const u32*   QW = (const u32*)d_in[1];
  const u32*   QZ = (const u32*)d_in[2];
  const float* SC = (const float*)d_in[3];
  const float* BI = (const float*)d_in[4];
  float* OUT = (float*)d_out;

  const size_t XB_BYTES = (size_t)M_DIMQ * K_DIM * 2;         // 33.5 MB
  const size_t WB_BYTES = (size_t)N_DIM * K_DIM * 2;          // 90.2 MB
  if (ws_size >= XB_BYTES + WB_BYTES) {
    u16* Xb = (u16*)d_ws;
    u16* Wb = (u16*)((char*)d_ws + XB_BYTES);
    cvt_x_perm<<<(M_DIMQ / 256) * 128 * 4, 256, 0, stream>>>(X, Xb);
    dq_w_perm<<<(N_DIM / 256) * 128 * 4, 256, 0, stream>>>(QW, QZ, SC, Wb);
    dim3 grid3(N_DIM / 256, M_DIMQ / 256);   // 43 x 16
    wq_gemm3<<<grid3, 512, 0, stream>>>(Xb, Wb, BI, OUT);
  } else {
    dim3 grid(N_DIM / 128, M_DIMQ / 128);    // 86 x 32
    wq_gemm<<<grid, 256, 0, stream>>>(X, QW, QZ, SC, BI, OUT);
  }
}